// Round 3
// baseline (10779.140 us; speedup 1.0000x reference)
//
#include <hip/hip_runtime.h>
#include <hip/hip_fp16.h>
#include <cstdint>
#include <cstddef>

// ---------------------------------------------------------------------------
// Tacotron2-style decoder, persistent kernel. 256 blocks x 512 threads,
// 1 block/CU (~157KB LDS). 2 phases per step: recurrent GEMMs fused
// (Wi0|Wh0 -> K=1792, Wi1|Wh1 -> K=2048). q = Wq@h0(t-1) computed
// REDUNDANTLY per attention block from a fp16 Wq workspace copy (no atomics
// -- the round-2 q rank-update atomic storm was the regression).
//   Phase A(t): attn(t)+q [blk 0-127, 32 pos each] || LSTM1(t-1) [128-255]
//   Phase B(t): LSTM0(t) [blk 0-127] || attw/cum [128-135] || outstop(t-1)
//               [136-216] || zero attc [217-224]
// ---------------------------------------------------------------------------

#define NB 256
#define NT 512

#define TE   512
#define DINz 512
#define TDz  150
#define ODz  80
#define DRz  1024
#define PREz 256
#define ATz  128
#define LOCz 32
#define KFz  31

// workspace offsets (floats)
#define OF_P     0         // prenet [1200][256]
#define OF_PM    307200    // pmT [128 blk][128 a][32 il]
#define OF_Q     831488    // (unused, kept for zero-range layout)
#define OF_U     833536    // u [8][512]
#define OF_CUM   837632    // att_cum [8][512]
#define OF_ATTC  841728    // unnormalized att_c [2][8][512] (atomic)
#define OF_ATTCN 849920    // normalized att_c [2][8][512] (for outstop)
#define OF_S     858112    // S [2][8]
#define OF_H0    858128    // h0 [2][8][1024]
#define OF_C0    874512    // c0 [8][1024]
#define OF_H1    882704    // h1 [2][8][1024]
#define OF_C1    899088    // c1 [8][1024]
#define OF_BAR   907280    // 1536 ints
#define OF_WQ16  908816    // fp16 Wq [128][1024] (131072 halves = 65536 f)

// LDS offsets (floats)
#define OFF_X0   0         // X chunk buf A [8][256] (also h0prev stage in A)
#define OFF_X1   2048      // X chunk buf B
#define OFF_EX   4096      // reduce exchange [256]
#define OFF_EXG  4352      // gate exchange [256]
#define OFF_W    4672      // fp16 weight tile: blk<128: 32x1792 (28672f);
                           //                   blk>=128: 32x2048 (32768f)
#define OFF_F    34368     // attn F = W_loc@filters (3968)
#define OFF_V    38336     // attn v (128)
#define OFF_CW   38464     // cum window (64)
#define OFF_QS   38528     // q slab (128)
#define OFF_PART 38656     // partials [32 il][16 ag] (512)
#define OFF_UU   39168     // u stage (32)
#define SM_TOTF  39200     // 156800 B

#define AG __HIP_MEMORY_SCOPE_AGENT

__device__ __forceinline__ float ldg_sc1(const float* p){
  return __hip_atomic_load(p, __ATOMIC_RELAXED, AG);
}
__device__ __forceinline__ void stg_sc1(float* p, float v){
  __hip_atomic_store(p, v, __ATOMIC_RELAXED, AG);
}
__device__ __forceinline__ float4 ldg4_sc1(const float* p){
  float4 r; r.x=ldg_sc1(p); r.y=ldg_sc1(p+1); r.z=ldg_sc1(p+2); r.w=ldg_sc1(p+3);
  return r;
}
__device__ __forceinline__ void stg4_sc1(float* p, float4 v){
  stg_sc1(p, v.x); stg_sc1(p+1, v.y); stg_sc1(p+2, v.z); stg_sc1(p+3, v.w);
}
__device__ __forceinline__ float fsig_(float x){ return 1.f/(1.f + __expf(-x)); }
__device__ __forceinline__ float ftanh_(float x){
  x = fminf(10.f, fmaxf(-10.f, x));
  float e = __expf(2.f*x);
  return (e - 1.f) / (e + 1.f);
}

// light barrier: replicated epochs (16 lines)
__device__ __forceinline__ void grid_barrier(int* bar){
  asm volatile("s_waitcnt vmcnt(0) lgkmcnt(0)" ::: "memory");
  __syncthreads();
  if (threadIdx.x == 0){
    const int lf = blockIdx.x >> 4;
    int* leaf  = bar + (lf << 5);
    int* root  = bar + 512;
    int* ep    = bar + 1024 + (lf << 5);
    int g = __hip_atomic_load(ep, __ATOMIC_RELAXED, AG);
    int lo = __hip_atomic_fetch_add(leaf, 1, __ATOMIC_RELAXED, AG);
    if ((lo & 15) == 15){
      int ro = __hip_atomic_fetch_add(root, 1, __ATOMIC_RELAXED, AG);
      if ((ro & 15) == 15){
        #pragma unroll
        for (int i=0;i<16;++i)
          __hip_atomic_store(bar + 1024 + (i<<5), g + 1, __ATOMIC_RELAXED, AG);
      }
    }
    while (__hip_atomic_load(ep, __ATOMIC_RELAXED, AG) == g)
      __builtin_amdgcn_s_sleep(1);
  }
  __syncthreads();
}
// heavy barrier (after init): flush cached init writes, invalidate
__device__ __forceinline__ void grid_barrier_heavy(int* bar){
  asm volatile("s_waitcnt vmcnt(0) lgkmcnt(0)" ::: "memory");
  __syncthreads();
  if (threadIdx.x == 0){
    __builtin_amdgcn_fence(__ATOMIC_RELEASE, "agent");
    const int lf = blockIdx.x >> 4;
    int* leaf  = bar + (lf << 5);
    int* root  = bar + 512;
    int* ep    = bar + 1024 + (lf << 5);
    int g = __hip_atomic_load(ep, __ATOMIC_RELAXED, AG);
    int lo = __hip_atomic_fetch_add(leaf, 1, __ATOMIC_RELAXED, AG);
    if ((lo & 15) == 15){
      int ro = __hip_atomic_fetch_add(root, 1, __ATOMIC_RELAXED, AG);
      if ((ro & 15) == 15){
        #pragma unroll
        for (int i=0;i<16;++i)
          __hip_atomic_store(bar + 1024 + (i<<5), g + 1, __ATOMIC_RELAXED, AG);
      }
    }
    while (__hip_atomic_load(ep, __ATOMIC_RELAXED, AG) == g)
      __builtin_amdgcn_s_sleep(1);
    __builtin_amdgcn_fence(__ATOMIC_ACQUIRE, "agent");
  }
  __syncthreads();
}

// init loaders: fused fp16 weight tiles (gate-mapped rows)
__device__ void load_wc0(float* smW, const float* __restrict__ Wi0,
                         const float* __restrict__ Wh0, int u0){
  __half* dst = (__half*)smW;
  for (int idx = threadIdx.x; idx < 32*448; idx += NT){
    int r = idx / 448, c4 = (idx - r*448) << 2;
    int grow = ((r>>3)<<10) + u0 + (r&7);
    const float* src = (c4 < 768) ? (Wi0 + (size_t)grow*768 + c4)
                                  : (Wh0 + (size_t)grow*1024 + (c4-768));
    float4 w = *(const float4*)src;
    __half* d = dst + (size_t)r*1792 + c4;
    d[0]=__float2half_rn(w.x); d[1]=__float2half_rn(w.y);
    d[2]=__float2half_rn(w.z); d[3]=__float2half_rn(w.w);
  }
}
__device__ void load_wc1(float* smW, const float* __restrict__ Wi1,
                         const float* __restrict__ Wh1, int u0){
  __half* dst = (__half*)smW;
  for (int idx = threadIdx.x; idx < 32*512; idx += NT){
    int r = idx >> 9, c4 = (idx & 511) << 2;
    int grow = ((r>>3)<<10) + u0 + (r&7);
    const float* src = (c4 < 1024) ? (Wi1 + (size_t)grow*1024 + c4)
                                   : (Wh1 + (size_t)grow*1024 + (c4-1024));
    float4 w = *(const float4*)src;
    __half* d = dst + (size_t)r*2048 + c4;
    d[0]=__float2half_rn(w.x); d[1]=__float2half_rn(w.y);
    d[2]=__float2half_rn(w.z); d[3]=__float2half_rn(w.w);
  }
}

// shuffle-reduce 32 k-slice partials -> dot for tid<256 (row=tid>>3, b=tid&7)
__device__ __forceinline__ float reduce_dot(float* sm, float (&acc)[2][8]){
  const int tid = threadIdx.x;
  const int s = tid & 31, pos = tid >> 5;
  #pragma unroll
  for (int i=0;i<2;++i){
    #pragma unroll
    for (int b=0;b<8;++b){
      float v = acc[i][b];
      v += __shfl_xor(v, 16, 64);
      v += __shfl_xor(v,  8, 64);
      v += __shfl_xor(v,  4, 64);
      v += __shfl_xor(v,  2, 64);
      v += __shfl_xor(v,  1, 64);
      acc[i][b] = v;
    }
  }
  if (s == 0){
    #pragma unroll
    for (int i=0;i<2;++i)
      #pragma unroll
      for (int b=0;b<8;++b)
        sm[OFF_EX + ((((pos<<1)+i)<<3) | b)] = acc[i][b];
  }
  __syncthreads();
  return (tid < 256) ? sm[OFF_EX + tid] : 0.f;
}

// GEMM: out[row 0..31][b 0..7] = sum_k Wlds[row][k] * X[b][k].
// W fp16 in LDS (gate-mapped). Caller provides all NCH X chunks in regs.
template<int NCH>
__device__ float gemm_core(float* sm, const __half* __restrict__ wlds,
                           float4 (&xreg)[NCH]){
  const int tid = threadIdx.x;
  const int s = tid & 31, pos = tid >> 5;
  const int xb = tid >> 6, xcol = (tid & 63) << 2;
  constexpr int K = NCH << 8;
  float acc[2][8];
  #pragma unroll
  for (int i=0;i<2;++i)
    #pragma unroll
    for (int b=0;b<8;++b) acc[i][b] = 0.f;
  *(float4*)&sm[OFF_X0 + (xb<<8) + xcol] = xreg[0];
  __syncthreads();
  #pragma unroll
  for (int ch=0; ch<NCH; ++ch){
    if (ch+1 < NCH)
      *(float4*)&sm[(((ch+1)&1) ? OFF_X1 : OFF_X0) + (xb<<8) + xcol] =
          xreg[(ch+1 < NCH) ? ch+1 : 0];
    const float* xbase = &sm[((ch&1) ? OFF_X1 : OFF_X0)];
    const __half* wch = wlds + (ch<<8);
    #pragma unroll
    for (int j=0;j<2;++j){
      const int k = (j<<7) + (s<<2);
      float4 xv[8];
      #pragma unroll
      for (int b=0;b<8;++b) xv[b] = *(const float4*)&xbase[(b<<8) + k];
      #pragma unroll
      for (int i=0;i<2;++i){
        const int row = (pos<<1) + i;
        uint2 w2 = *(const uint2*)&wch[(size_t)row*K + k];
        __half2 ha = *reinterpret_cast<const __half2*>(&w2.x);
        __half2 hb = *reinterpret_cast<const __half2*>(&w2.y);
        float2 fa = __half22float2(ha);
        float2 fb = __half22float2(hb);
        #pragma unroll
        for (int b=0;b<8;++b){
          acc[i][b] = fmaf(fa.x, xv[b].x, acc[i][b]);
          acc[i][b] = fmaf(fa.y, xv[b].y, acc[i][b]);
          acc[i][b] = fmaf(fb.x, xv[b].z, acc[i][b]);
          acc[i][b] = fmaf(fb.y, xv[b].w, acc[i][b]);
        }
      }
    }
    __syncthreads();
  }
  return reduce_dot(sm, acc);
}

// issue the epilogue's old-h load BEFORE the GEMM so its latency hides
__device__ __forceinline__ float prefetch_h(const float* h, int u0){
  const int tid = threadIdx.x;
  if (tid >= 64) return 0.f;
  return ldg_sc1(&h[((tid&7)<<10) + u0 + (tid>>3)]);
}

// one output row per wave: rr = b*81 + r (r==80 -> stop). attcn pre-normalized.
__device__ void outstop_wave(int rr, int tp,
    const float* __restrict__ feat_W, const float* __restrict__ stop_W,
    const float* __restrict__ stop_b, const float* __restrict__ h1b,
    const float* __restrict__ attcn, float* __restrict__ d_out)
{
  if (rr >= 648) return;
  int b = rr / 81, r = rr - 81*b;
  int lane = threadIdx.x & 63;
  const float4* Wr = (const float4*)((r < 80) ? (feat_W + (size_t)r*1536) : stop_W);
  float acc = 0.f;
  #pragma unroll
  for (int j=0;j<4;++j){
    int p = lane + (j<<6);
    float4 w = Wr[p], x = ldg4_sc1(h1b + (b<<10) + (p<<2));
    acc = fmaf(w.x,x.x, fmaf(w.y,x.y, fmaf(w.z,x.z, fmaf(w.w,x.w, acc))));
  }
  #pragma unroll
  for (int j=4;j<6;++j){
    int p = lane + (j<<6);
    float4 w = Wr[p], x = ldg4_sc1(attcn + (b<<9) + ((p-256)<<2));
    acc = fmaf(w.x,x.x, fmaf(w.y,x.y, fmaf(w.z,x.z, fmaf(w.w,x.w, acc))));
  }
  acc += __shfl_down(acc, 32, 64);
  acc += __shfl_down(acc, 16, 64);
  acc += __shfl_down(acc,  8, 64);
  acc += __shfl_down(acc,  4, 64);
  acc += __shfl_down(acc,  2, 64);
  acc += __shfl_down(acc,  1, 64);
  if (lane == 0){
    if (r < 80) d_out[((size_t)b*TDz + tp)*ODz + r] = acc;
    else        d_out[96000 + (size_t)b*TDz + tp] = acc + stop_b[0];
  }
}

extern "C" __global__ void __launch_bounds__(NT, 1) dec_kernel(
  const float* __restrict__ memory, const int* __restrict__ mlen, const float* __restrict__ targets,
  const float* __restrict__ W_mem, const float* __restrict__ W_q, const float* __restrict__ W_loc,
  const float* __restrict__ loc_f, const float* __restrict__ attn_v, const float* __restrict__ attn_b,
  const float* __restrict__ pre_W1, const float* __restrict__ pre_b1,
  const float* __restrict__ pre_W2, const float* __restrict__ pre_b2,
  const float* __restrict__ Wi0, const float* __restrict__ Wh0, const float* __restrict__ bl0,
  const float* __restrict__ Wi1, const float* __restrict__ Wh1, const float* __restrict__ bl1,
  const float* __restrict__ feat_W, const float* __restrict__ stop_W, const float* __restrict__ stop_b,
  float* __restrict__ d_out, float* __restrict__ ws)
{
  __shared__ float sm[SM_TOTF];
  const int blk = blockIdx.x, tid = threadIdx.x;

  float* Pw   = ws + OF_P;
  float* pmT  = ws + OF_PM;
  float* uw   = ws + OF_U;
  float* cum  = ws + OF_CUM;
  float* attc = ws + OF_ATTC;
  float* attcn= ws + OF_ATTCN;
  float* Sw   = ws + OF_S;
  float* h0 = ws + OF_H0; float* c0 = ws + OF_C0;
  float* h1 = ws + OF_H1; float* c1 = ws + OF_C1;
  int* bar = (int*)(ws + OF_BAR);
  const __half* wq16 = (const __half*)(ws + OF_WQ16);

  const bool is_attn = (blk < 128);
  const int ab  = blk >> 4;          // attention batch
  const int ai0 = (blk & 15) << 5;   // attention base position (32-wide)
  const int il  = tid & 31;          // position within slice
  const int ag  = tid >> 5;          // feature group (0..15)

  // ------------------------- INIT (every launch) ---------------------------
  {
    const int gs = NB*NT;
    const int gid = blk*NT + tid;
    // zero all dynamic state (contiguous region)
    for (int i = gid; i < (OF_BAR - OF_Q); i += gs) ws[OF_Q + i] = 0.f;
    // fp16 Wq copy (gs == 131072 exactly: one element per thread)
    { __half* wqd = (__half*)(ws + OF_WQ16);
      for (int i = gid; i < 131072; i += gs) wqd[i] = __float2half_rn(W_q[i]); }

    // persistent fp16 weight tiles
    if (is_attn) load_wc0(&sm[OFF_W], Wi0, Wh0, blk<<3);
    else         load_wc1(&sm[OFF_W], Wi1, Wh1, (blk-128)<<3);

    if (is_attn){
      // pmT[a][il] = mem[ab, ai0+il, :] . W_mem[a,:] + attn_b[a]
      float pacc[8];
      #pragma unroll
      for (int j=0;j<8;++j) pacc[j] = 0.f;
      for (int dc=0; dc<4; ++dc){
        for (int idx = tid; idx < 4096; idx += NT){
          int r = idx >> 7, d = idx & 127;
          sm[r*129 + d] = memory[(size_t)((ab<<9)+ai0+r)*DINz + (dc<<7) + d];
        }
        __syncthreads();
        #pragma unroll
        for (int j=0;j<8;++j){
          int a = (ag<<3) + j;
          const float* wr = W_mem + (size_t)a*DINz + (dc<<7);
          const float* mr = &sm[il*129];
          float acc = 0.f;
          for (int d=0; d<128; d+=4){
            acc = fmaf(mr[d  ], wr[d  ], acc);
            acc = fmaf(mr[d+1], wr[d+1], acc);
            acc = fmaf(mr[d+2], wr[d+2], acc);
            acc = fmaf(mr[d+3], wr[d+3], acc);
          }
          pacc[j] += acc;
        }
        __syncthreads();
      }
      #pragma unroll
      for (int j=0;j<8;++j){
        int a = (ag<<3) + j;
        pmT[((size_t)blk<<12) + (a<<5) + il] = pacc[j] + attn_b[a];
      }
      // persistent slabs: F = W_loc @ filters, v
      for (int idx = tid; idx < ATz*KFz; idx += NT){
        int a = idx / KFz, k = idx - a*KFz;
        float s2 = 0.f;
        #pragma unroll
        for (int c2=0;c2<LOCz;++c2) s2 = fmaf(W_loc[(a<<5)+c2], loc_f[c2*KFz+k], s2);
        sm[OFF_F + idx] = s2;
      }
      if (tid < 128) sm[OFF_V + tid] = attn_v[tid];
      __syncthreads();
    }

    // prenet for all (t,b) pairs; scratch in sm[0..1023]
    const int th = tid >> 8, t2 = tid & 255, base = th << 9;
    for (int it=0; it<3; ++it){
      int pp2 = (blk<<1) + th + (it<<9);
      bool act = pp2 < 1200;
      if (act && t2 < ODz){
        int tt = pp2 >> 3, bb = pp2 & 7;
        sm[base + t2] = (tt==0) ? 0.f : targets[((size_t)bb*TDz + (tt-1))*ODz + t2];
      }
      __syncthreads();
      if (act){
        float a1 = pre_b1[t2];
        for (int k=0;k<ODz;++k) a1 = fmaf(pre_W1[t2*ODz+k], sm[base+k], a1);
        sm[base + 128 + t2] = fmaxf(a1, 0.f);
      }
      __syncthreads();
      if (act){
        float a2 = pre_b2[t2];
        for (int k=0;k<PREz;++k) a2 = fmaf(pre_W2[(t2<<8)+k], sm[base+128+k], a2);
        Pw[((size_t)pp2<<8) + t2] = fmaxf(a2, 0.f);
      }
      __syncthreads();
    }
  }
  grid_barrier_heavy(bar);

  // ------------------------------ MAIN LOOP (2 phases) ---------------------
  for (int t = 0; t < TDz; ++t){
    const int p = t & 1, pp = p ^ 1;

    // ---- Phase A: attn(t)+q [0-127] | LSTM1(t-1) [128-255] ----------------
    if (is_attn){
      // stage cum window + h0(t-1)[ab] into LDS
      if (tid < 62){
        int gi = ai0 - 15 + tid;
        sm[OFF_CW + tid] = (gi >= 0 && gi < TE) ? ldg_sc1(&cum[(ab<<9)+gi]) : 0.f;
      }
      {
        const float* h0prev = h0 + (pp<<13) + (ab<<10);
        for (int i = tid; i < 1024; i += NT) sm[OFF_X0 + i] = ldg_sc1(&h0prev[i]);
      }
      __syncthreads();
      // q[a] = Wq[a,:] . h0prev  (wave wv does a = j*8+wv; x held in regs)
      {
        const int wv = tid >> 6, lane = tid & 63;
        float xsr[16];
        #pragma unroll
        for (int i=0;i<2;++i){
          float4 v0 = *(const float4*)&sm[OFF_X0 + (i<<9) + (lane<<3)];
          float4 v1 = *(const float4*)&sm[OFF_X0 + (i<<9) + (lane<<3) + 4];
          xsr[(i<<3)+0]=v0.x; xsr[(i<<3)+1]=v0.y; xsr[(i<<3)+2]=v0.z; xsr[(i<<3)+3]=v0.w;
          xsr[(i<<3)+4]=v1.x; xsr[(i<<3)+5]=v1.y; xsr[(i<<3)+6]=v1.z; xsr[(i<<3)+7]=v1.w;
        }
        #pragma unroll 2
        for (int j=0;j<16;++j){
          int a = (j<<3) + wv;
          float acc = 0.f;
          #pragma unroll
          for (int i=0;i<2;++i){
            uint4 u = *(const uint4*)(wq16 + ((size_t)a<<10) + (i<<9) + (lane<<3));
            float2 f0 = __half22float2(*reinterpret_cast<__half2*>(&u.x));
            float2 f1 = __half22float2(*reinterpret_cast<__half2*>(&u.y));
            float2 f2 = __half22float2(*reinterpret_cast<__half2*>(&u.z));
            float2 f3 = __half22float2(*reinterpret_cast<__half2*>(&u.w));
            acc = fmaf(f0.x, xsr[(i<<3)+0], acc); acc = fmaf(f0.y, xsr[(i<<3)+1], acc);
            acc = fmaf(f1.x, xsr[(i<<3)+2], acc); acc = fmaf(f1.y, xsr[(i<<3)+3], acc);
            acc = fmaf(f2.x, xsr[(i<<3)+4], acc); acc = fmaf(f2.y, xsr[(i<<3)+5], acc);
            acc = fmaf(f3.x, xsr[(i<<3)+6], acc); acc = fmaf(f3.y, xsr[(i<<3)+7], acc);
          }
          acc += __shfl_xor(acc, 32, 64);
          acc += __shfl_xor(acc, 16, 64);
          acc += __shfl_xor(acc,  8, 64);
          acc += __shfl_xor(acc,  4, 64);
          acc += __shfl_xor(acc,  2, 64);
          acc += __shfl_xor(acc,  1, 64);
          if (lane == 0) sm[OFF_QS + a] = acc;
        }
      }
      __syncthreads();
      // energies + softmax numerators + partial att_c
      float part = 0.f;
      #pragma unroll
      for (int j=0;j<8;++j){
        int a = (ag<<3) + j;
        const float* fb = &sm[OFF_F + a*KFz];
        float conv = 0.f;
        #pragma unroll
        for (int k=0;k<KFz;++k) conv = fmaf(fb[k], sm[OFF_CW + il + k], conv);
        float pv = pmT[((size_t)blk<<12) + (a<<5) + il];
        part = fmaf(sm[OFF_V + a], ftanh_(pv + sm[OFF_QS + a] + conv), part);
      }
      sm[OFF_PART + (il<<4) + ag] = part;
      __syncthreads();
      if (tid < 32){
        float e = 0.f;
        #pragma unroll
        for (int k=0;k<16;++k) e += sm[OFF_PART + (tid<<4) + k];
        int gi = ai0 + tid;
        float uu = (gi < mlen[ab]) ? __expf(e) : 0.f;
        stg_sc1(&uw[(ab<<9)+gi], uu);
        sm[OFF_UU + tid] = uu;
      }
      __syncthreads();
      if (tid == 0){
        float ssum = 0.f;
        #pragma unroll
        for (int k=0;k<32;++k) ssum += sm[OFF_UU + k];
        atomicAdd(&Sw[(p<<3)+ab], ssum);
      }
      {
        float acc = 0.f;
        const float* mrow = memory + (size_t)((ab<<9)+ai0)*DINz + tid;
        #pragma unroll 8
        for (int i=0;i<32;++i)
          acc = fmaf(sm[OFF_UU + i], mrow[(size_t)i*DINz], acc);
        atomicAdd(&attc[(p<<12) + (ab<<9) + tid], acc);
      }
    } else {
      if (blk == 128 && tid < 8) stg_sc1(&Sw[(pp<<3)+tid], 0.f);  // for A(t+1)
      if (t > 0){
        // LSTM1(t-1): X = [h0(t-1)=h0[pp] | h1(t-2)=h1[p]], writes h1[pp]
        const int u0 = (blk - 128) << 3;
        const float* h0pp = h0 + (pp<<13);
        const float* h1p  = h1 + (p<<13);
        const int xb = tid >> 6, xcol = (tid & 63) << 2;
        float hold = prefetch_h(h1p, u0);
        float4 xr[8];
        #pragma unroll
        for (int c=0;c<4;++c) xr[c]   = ldg4_sc1(h0pp + (xb<<10) + (c<<8) + xcol);
        #pragma unroll
        for (int c=0;c<4;++c) xr[4+c] = ldg4_sc1(h1p  + (xb<<10) + (c<<8) + xcol);
        float dot = gemm_core<8>(sm, (const __half*)&sm[OFF_W], xr);
        if (tid < 256){
          int row32 = tid >> 3, gate = row32 >> 3, ul = row32 & 7;
          sm[OFF_EXG + tid] = dot + bl1[(gate<<10) + u0 + ul];
        }
        __syncthreads();
        if (tid < 64){
          float gi = sm[OFF_EXG + tid];
          float gf = sm[OFF_EXG + 64 + tid];
          float gg = sm[OFF_EXG + 128 + tid];
          float go = sm[OFF_EXG + 192 + tid];
          int ul2 = tid >> 3, b2 = tid & 7;
          int hi = (b2<<10) + u0 + ul2;
          float co = c1[hi];
          float cn = fsig_(gf)*co + fsig_(gi)*ftanh_(gg);
          float hn = fsig_(go)*ftanh_(cn);
          c1[hi] = 0.9f*cn + 0.1f*co;
          stg_sc1(h1 + (pp<<13) + hi, 0.9f*hn + 0.1f*hold);
        }
      }
    }
    grid_barrier(bar);

    // ---- Phase B: LSTM0(t) [0-127] | attw/cum [128-135] |
    //               outstop(t-1) [136-216] | zero attc [217-224] ------------
    if (is_attn){
      // LSTM0(t): X = [attc(t)/S | prenet(t) | h0(t-1)=h0[pp]], writes h0[p]
      const int u0 = blk << 3;
      const int xb = tid >> 6, xcol = (tid & 63) << 2;
      float* attc_p = attc + (p<<12);
      const float* h0pp = h0 + (pp<<13);
      float sv = ldg_sc1(Sw + (p<<3) + xb);
      float hold = prefetch_h(h0pp, u0);
      float4 xr[7];
      xr[0] = ldg4_sc1(attc_p + (xb<<9) + xcol);
      xr[1] = ldg4_sc1(attc_p + (xb<<9) + 256 + xcol);
      xr[2] = *(const float4*)(Pw + ((size_t)t<<11) + (xb<<8) + xcol);
      #pragma unroll
      for (int c=0;c<4;++c) xr[3+c] = ldg4_sc1(h0pp + (xb<<10) + (c<<8) + xcol);
      float inv = 1.f / sv;
      xr[0].x*=inv; xr[0].y*=inv; xr[0].z*=inv; xr[0].w*=inv;
      xr[1].x*=inv; xr[1].y*=inv; xr[1].z*=inv; xr[1].w*=inv;
      if (blk == 0){  // publish normalized att_c for outstop(t) in B(t+1)
        float* an = attcn + (p<<12) + (xb<<9) + xcol;
        stg4_sc1(an, xr[0]);
        stg4_sc1(an + 256, xr[1]);
      }
      float dot = gemm_core<7>(sm, (const __half*)&sm[OFF_W], xr);
      if (tid < 256){
        int row32 = tid >> 3, gate = row32 >> 3, ul = row32 & 7;
        sm[OFF_EXG + tid] = dot + bl0[(gate<<10) + u0 + ul];
      }
      __syncthreads();
      if (tid < 64){
        float gi = sm[OFF_EXG + tid];
        float gf = sm[OFF_EXG + 64 + tid];
        float gg = sm[OFF_EXG + 128 + tid];
        float go = sm[OFF_EXG + 192 + tid];
        int ul2 = tid >> 3, b2 = tid & 7;
        int hi = (b2<<10) + u0 + ul2;
        float co = c0[hi];
        float cn = fsig_(gf)*co + fsig_(gi)*ftanh_(gg);
        float hn = fsig_(go)*ftanh_(cn);
        c0[hi] = 0.9f*cn + 0.1f*co;
        stg_sc1(h0 + (p<<13) + hi, 0.9f*hn + 0.1f*hold);
      }
    } else if (blk < 136){
      const int b = blk - 128;
      float Sv = __hip_atomic_load(&Sw[(p<<3)+b], __ATOMIC_RELAXED, AG);
      float inv = 1.f / Sv;
      for (int i = tid; i < TE; i += NT){
        float u = ldg_sc1(&uw[(b<<9)+i]);
        float w = u * inv;
        d_out[97200 + ((size_t)b*TDz + t)*TE + i] = w;
        stg_sc1(&cum[(b<<9)+i], ldg_sc1(&cum[(b<<9)+i]) + w);
      }
    } else if (blk < 217){
      if (t > 0)
        outstop_wave((blk-136)*8 + (tid>>6), t-1,
                     feat_W, stop_W, stop_b, h1 + (pp<<13), attcn + (pp<<12), d_out);
    } else if (blk < 225){
      // zero attc[pp] (accumulated next in A(t+1))
      stg_sc1(&attc[(pp<<12) + ((blk-217)<<9) + tid], 0.f);
    }
    grid_barrier(bar);
  }

  // ---- epilogue: LSTM1(149) then outstop(149).  t=150 -> p=0, pp=1 --------
  if (!is_attn){
    const int u0 = (blk - 128) << 3;
    const float* h0pp = h0 + (1<<13);   // h0(149)
    const float* h1p  = h1 + (0<<13);   // h1(148)
    const int xb = tid >> 6, xcol = (tid & 63) << 2;
    float hold = prefetch_h(h1p, u0);
    float4 xr[8];
    #pragma unroll
    for (int c=0;c<4;++c) xr[c]   = ldg4_sc1(h0pp + (xb<<10) + (c<<8) + xcol);
    #pragma unroll
    for (int c=0;c<4;++c) xr[4+c] = ldg4_sc1(h1p  + (xb<<10) + (c<<8) + xcol);
    float dot = gemm_core<8>(sm, (const __half*)&sm[OFF_W], xr);
    if (tid < 256){
      int row32 = tid >> 3, gate = row32 >> 3, ul = row32 & 7;
      sm[OFF_EXG + tid] = dot + bl1[(gate<<10) + u0 + ul];
    }
    __syncthreads();
    if (tid < 64){
      float gi = sm[OFF_EXG + tid];
      float gf = sm[OFF_EXG + 64 + tid];
      float gg = sm[OFF_EXG + 128 + tid];
      float go = sm[OFF_EXG + 192 + tid];
      int ul2 = tid >> 3, b2 = tid & 7;
      int hi = (b2<<10) + u0 + ul2;
      float co = c1[hi];
      float cn = fsig_(gf)*co + fsig_(gi)*ftanh_(gg);
      float hn = fsig_(go)*ftanh_(cn);
      stg_sc1(h1 + (1<<13) + hi, 0.9f*hn + 0.1f*hold);
    }
  }
  grid_barrier(bar);
  if (blk >= 136 && blk < 217)
    outstop_wave((blk-136)*8 + (tid>>6), TDz-1,
                 feat_W, stop_W, stop_b, h1 + (1<<13), attcn + (1<<12), d_out);
}

extern "C" void kernel_launch(void* const* d_in, const int* in_sizes, int n_in,
                              void* d_out, int out_size, void* d_ws, size_t ws_size,
                              hipStream_t stream)
{
  (void)in_sizes; (void)n_in; (void)out_size; (void)ws_size;
  (void)hipMemsetAsync((char*)d_ws + (size_t)OF_BAR*4, 0, 6144, stream);
  dec_kernel<<<dim3(NB), dim3(NT), 0, stream>>>(
    (const float*)d_in[0],  (const int*)d_in[1],   (const float*)d_in[2],
    (const float*)d_in[3],  (const float*)d_in[4],  (const float*)d_in[5],
    (const float*)d_in[6],  (const float*)d_in[7],  (const float*)d_in[8],
    (const float*)d_in[9],  (const float*)d_in[10], (const float*)d_in[11], (const float*)d_in[12],
    (const float*)d_in[13], (const float*)d_in[14], (const float*)d_in[15],
    (const float*)d_in[16], (const float*)d_in[17], (const float*)d_in[18],
    (const float*)d_in[19], (const float*)d_in[20], (const float*)d_in[21],
    (float*)d_out, (float*)d_ws);
}

// Round 4
// 5174.709 us; speedup vs baseline: 2.0830x; 2.0830x over previous
//
#include <hip/hip_runtime.h>
#include <hip/hip_fp16.h>
#include <cstdint>
#include <cstddef>

// ---------------------------------------------------------------------------
// Tacotron2-style decoder, persistent kernel. 256 blocks x 512 threads,
// 1 block/CU (150KB LDS). All five weight matrices live in LDS as fp16 for
// the whole kernel (role-balanced tiles <=128KB/block + staging). 3 phases
// per step; cross-block state via sc1 (LLC).
// This round's single change vs the verified 5674us kernel: the grid barrier
// is store/scan based (per-block arrival slots on private cache lines + one
// scanner block + replicated epoch broadcast) instead of fetch_add trees --
// same-address RMW chains serialized ~4-5us per barrier at the LLC.
// Roles: blk 0-63  : P1 attn      | P2 LSTM0 | P3 gh0 tile blk      (Wi0+Wh0)
//        blk 64-67 : P1 gh0 tail  | P2 LSTM0 | P3 gh0 tile blk      (Wi0+Wh0; tail W streamed fp32)
//        blk 68-123:               P2 LSTM0 | P3 gh0 tile blk      (Wi0+Wh0)
//        blk 124-127:              P2 LSTM0 | P3 Wq tile + zeroing  (Wi0+Wq)
//        blk 128-255: P1 gh1      | P2 attw/outstop | P3 LSTM1      (Wh1+Wi1)
// ---------------------------------------------------------------------------

#define NB 256
#define NT 512

#define Bz   8
#define TE   512
#define DINz 512
#define TDz  150
#define ODz  80
#define DRz  1024
#define PREz 256
#define ATz  128
#define LOCz 32
#define KFz  31

// workspace offsets (floats)
#define OF_P    0            // prenet [1200][256]
#define OF_PM   307200       // pmT per attention block [64][128a][64il]
#define OF_Q    831488       // q [128a][8b]
#define OF_U    832512       // u [8][512]
#define OF_CUM  836608       // att_cum [8][512]
#define OF_ATTC 840704       // unnormalized att_c [2][8][512]
#define OF_S    848896       // S [2][8]
#define OF_INVS 848912       // 1/S [2][8]
#define OF_H0   848928
#define OF_C0   857120
#define OF_H1   865312
#define OF_C1   873504
#define OF_GH0  881696       // gh0 [4096][8]
#define OF_GH1  914464       // gh1 [4096][8]
#define OF_BAR  947232       // 4608 ints: slots[256*16] | epochs@4096+grp*16

// shared-memory offsets (floats)
#define OFF_X0   0           // X chunk buffer A [8][256]
#define OFF_X1   2048        // X chunk buffer B
#define OFF_EX   4096        // reduce exchange [256]
#define OFF_EXG  4352        // gate exchange [256]
#define OFF_CW   4608        // attn cum window [96] (blk<64, P1 only)
#define OFF_QS   4736        // attn q slab [128]
#define OFF_PART 4864        // attn partials [64][8]
#define OFF_UU   5376        // attn u stage [64]
#define OFF_F    5632        // attn F = W_loc@filters [128*31]
#define OFF_V    9600        // attn v [128]
#define OFF_WA   9728        // blk<128: fp16 Wi0 tile 32x768   (12288 f)
#define OFF_WB   22016       // blk<128: fp16 Wh0/Wq tile 32x1024 (16384 f)
#define OFF_WG1  4608        // blk>=128: fp16 Wh1 tile 32x1024 (16384 f)
#define OFF_WG2  20992       // blk>=128: fp16 Wi1 tile 32x1024 (16384 f)
#define SM_TOTF  38400       // 153600 B

#define AG __HIP_MEMORY_SCOPE_AGENT

__device__ __forceinline__ float ldg_sc1(const float* p){
  return __hip_atomic_load(p, __ATOMIC_RELAXED, AG);
}
__device__ __forceinline__ void stg_sc1(float* p, float v){
  __hip_atomic_store(p, v, __ATOMIC_RELAXED, AG);
}
__device__ __forceinline__ float4 ldg4_sc1(const float* p){
  float4 r; r.x=ldg_sc1(p); r.y=ldg_sc1(p+1); r.z=ldg_sc1(p+2); r.w=ldg_sc1(p+3);
  return r;
}
__device__ __forceinline__ float fsig_(float x){ return 1.f/(1.f + __expf(-x)); }
__device__ __forceinline__ float ftanh_(float x){
  x = fminf(10.f, fmaxf(-10.f, x));
  float e = __expf(2.f*x);
  return (e - 1.f) / (e + 1.f);
}

// -------- store/scan grid barrier (no RMW contention) ----------------------
// arrival: thread0 stores monotonic target to its block's private slot line.
// block 255 scans all 256 slots (256 threads, one load each) until all have
// arrived, then broadcasts target to 16 replicated epoch lines.
// waiters poll their group's epoch line.
__device__ __forceinline__ void grid_barrier(int* bar, int target){
  asm volatile("s_waitcnt vmcnt(0) lgkmcnt(0)" ::: "memory");
  __syncthreads();
  const int tid = threadIdx.x;
  if (tid == 0)
    __hip_atomic_store(bar + (blockIdx.x << 4), target, __ATOMIC_RELAXED, AG);
  if (blockIdx.x == 255){
    for (;;){
      int ok = 1;
      if (tid < 256)
        ok = (__hip_atomic_load(bar + (tid << 4), __ATOMIC_RELAXED, AG) >= target);
      if (__syncthreads_and(ok)) break;
    }
    if (tid < 16)
      __hip_atomic_store(bar + 4096 + (tid << 4), target, __ATOMIC_RELAXED, AG);
  }
  if (tid == 0){
    int* ep = bar + 4096 + ((blockIdx.x >> 4) << 4);
    while (__hip_atomic_load(ep, __ATOMIC_RELAXED, AG) < target)
      __builtin_amdgcn_s_sleep(1);
  }
  __syncthreads();
}
// heavy barrier (after init only): flush cached init writes, invalidate
__device__ __forceinline__ void grid_barrier_heavy(int* bar, int target){
  asm volatile("s_waitcnt vmcnt(0) lgkmcnt(0)" ::: "memory");
  __syncthreads();
  const int tid = threadIdx.x;
  if (tid == 0)
    __builtin_amdgcn_fence(__ATOMIC_RELEASE, "agent");
  __syncthreads();
  if (tid == 0)
    __hip_atomic_store(bar + (blockIdx.x << 4), target, __ATOMIC_RELAXED, AG);
  if (blockIdx.x == 255){
    for (;;){
      int ok = 1;
      if (tid < 256)
        ok = (__hip_atomic_load(bar + (tid << 4), __ATOMIC_RELAXED, AG) >= target);
      if (__syncthreads_and(ok)) break;
    }
    if (tid < 16)
      __hip_atomic_store(bar + 4096 + (tid << 4), target, __ATOMIC_RELAXED, AG);
  }
  if (tid == 0){
    int* ep = bar + 4096 + ((blockIdx.x >> 4) << 4);
    while (__hip_atomic_load(ep, __ATOMIC_RELAXED, AG) < target)
      __builtin_amdgcn_s_sleep(1);
    __builtin_amdgcn_fence(__ATOMIC_ACQUIRE, "agent");
  }
  __syncthreads();
}

// init: load 32xK fp32 tile from global -> fp16 LDS (optionally gate-mapped,
// so runtime GEMM reads are linear rows)
template<int K, bool GM>
__device__ void load_wtile(float* dstf, const float* __restrict__ W, int base){
  __half* dst = (__half*)dstf;
  constexpr int KV = K >> 2;
  constexpr int NV = 32 * KV;
  for (int idx = threadIdx.x; idx < NV; idx += NT){
    int r = idx / KV;
    int c = (idx - r*KV) << 2;
    int grow = GM ? (((r>>3)<<10) + base + (r&7)) : (base + r);
    float4 w = *(const float4*)(W + (size_t)grow*K + c);
    __half* d = dst + (size_t)r*K + c;
    d[0] = __float2half_rn(w.x);
    d[1] = __float2half_rn(w.y);
    d[2] = __float2half_rn(w.z);
    d[3] = __float2half_rn(w.w);
  }
}

// reduce 32 k-slice partials (within 32-lane half-waves) -> dot for tid<256,
// laid out as row = tid>>3, b = tid&7
__device__ __forceinline__ float reduce_dot(float* sm, float (&acc)[2][8]){
  const int tid = threadIdx.x;
  const int s = tid & 31, pos = tid >> 5;
  #pragma unroll
  for (int i=0;i<2;++i){
    #pragma unroll
    for (int b=0;b<8;++b){
      float v = acc[i][b];
      v += __shfl_xor(v, 16, 64);
      v += __shfl_xor(v,  8, 64);
      v += __shfl_xor(v,  4, 64);
      v += __shfl_xor(v,  2, 64);
      v += __shfl_xor(v,  1, 64);
      acc[i][b] = v;
    }
  }
  if (s == 0){
    #pragma unroll
    for (int i=0;i<2;++i)
      #pragma unroll
      for (int b=0;b<8;++b)
        sm[OFF_EX + ((((pos<<1)+i)<<3) | b)] = acc[i][b];
  }
  __syncthreads();
  return (tid < 256) ? sm[OFF_EX + tid] : 0.f;
}

// GEMM tile: out[row 0..31][b 0..7] = sum_k Wlds[row][k] * X[b][k]
// W resident in LDS (fp16, gate-mapping already applied). X double-buffered,
// 1 barrier per 256-wide chunk. XMODE 0: X = xsrc (sc1). XMODE 1: X =
// [attc*(1/S) | prenet].
template<int K, int XMODE>
__device__ float gemm32x8_lds(float* sm, const __half* __restrict__ wlds,
                              const float* __restrict__ xsrc,
                              const float* __restrict__ attc_cur,
                              const float* __restrict__ S_cur,
                              const float* __restrict__ Pt)
{
  constexpr int NCH = K >> 8;
  const int tid = threadIdx.x;
  const int s = tid & 31, pos = tid >> 5;
  float acc[2][8];
  #pragma unroll
  for (int i=0;i<2;++i)
    #pragma unroll
    for (int b=0;b<8;++b) acc[i][b] = 0.f;

  const int xb = tid >> 6, xcol = (tid & 63) << 2;
  float4 xreg[NCH];
  if constexpr (XMODE == 0){
    #pragma unroll
    for (int ch=0; ch<NCH; ++ch)
      xreg[ch] = ldg4_sc1(xsrc + (size_t)xb*K + (ch<<8) + xcol);
  } else {
    float xsc = 1.f / ldg_sc1(S_cur + xb);
    #pragma unroll
    for (int ch=0; ch<2; ++ch){
      float4 v = ldg4_sc1(attc_cur + (xb<<9) + (ch<<8) + xcol);
      v.x*=xsc; v.y*=xsc; v.z*=xsc; v.w*=xsc;
      xreg[ch] = v;
    }
    xreg[2] = *(const float4*)(Pt + (xb<<8) + xcol);
  }
  *(float4*)&sm[OFF_X0 + (xb<<8) + xcol] = xreg[0];
  __syncthreads();
  #pragma unroll
  for (int ch=0; ch<NCH; ++ch){
    if (ch+1 < NCH)
      *(float4*)&sm[(((ch+1)&1) ? OFF_X1 : OFF_X0) + (xb<<8) + xcol] = xreg[(ch+1 < NCH) ? ch+1 : 0];
    const float* xbase = &sm[((ch&1) ? OFF_X1 : OFF_X0)];
    const __half* wch = wlds + (ch<<8);
    #pragma unroll
    for (int j=0;j<2;++j){
      const int k = (j<<7) + (s<<2);
      float4 xv[8];
      #pragma unroll
      for (int b=0;b<8;++b) xv[b] = *(const float4*)&xbase[(b<<8) + k];
      #pragma unroll
      for (int i=0;i<2;++i){
        const int row = (pos<<1) + i;
        uint2 w2 = *(const uint2*)&wch[(size_t)row*K + k];
        __half2 ha = *reinterpret_cast<const __half2*>(&w2.x);
        __half2 hb = *reinterpret_cast<const __half2*>(&w2.y);
        float2 fa = __half22float2(ha);
        float2 fb = __half22float2(hb);
        #pragma unroll
        for (int b=0;b<8;++b){
          acc[i][b] = fmaf(fa.x, xv[b].x, acc[i][b]);
          acc[i][b] = fmaf(fa.y, xv[b].y, acc[i][b]);
          acc[i][b] = fmaf(fb.x, xv[b].z, acc[i][b]);
          acc[i][b] = fmaf(fb.y, xv[b].w, acc[i][b]);
        }
      }
    }
    __syncthreads();
  }
  return reduce_dot(sm, acc);
}

// streamed-W variant (fp32 W straight from global to registers; exactly
// tiled, no duplication). Used only by the 4 P1 gh0-tail blocks.
__device__ float gemm32x8_gw(float* sm, const float* __restrict__ W, int rowbase,
                             const float* __restrict__ xsrc)
{
  const int tid = threadIdx.x;
  const int s = tid & 31, pos = tid >> 5;
  float acc[2][8];
  #pragma unroll
  for (int i=0;i<2;++i)
    #pragma unroll
    for (int b=0;b<8;++b) acc[i][b] = 0.f;
  const int xb = tid >> 6, xcol = (tid & 63) << 2;
  float4 xreg[4];
  #pragma unroll
  for (int ch=0; ch<4; ++ch)
    xreg[ch] = ldg4_sc1(xsrc + (size_t)xb*1024 + (ch<<8) + xcol);
  const float* w0 = W + (size_t)(rowbase + (pos<<1))*1024 + (s<<2);
  *(float4*)&sm[OFF_X0 + (xb<<8) + xcol] = xreg[0];
  __syncthreads();
  #pragma unroll
  for (int ch=0; ch<4; ++ch){
    float4 wr[2][2];
    #pragma unroll
    for (int j=0;j<2;++j)
      #pragma unroll
      for (int i=0;i<2;++i)
        wr[j][i] = *(const float4*)(w0 + (size_t)i*1024 + (ch<<8) + (j<<7));
    if (ch+1 < 4)
      *(float4*)&sm[(((ch+1)&1) ? OFF_X1 : OFF_X0) + (xb<<8) + xcol] = xreg[(ch+1<4)?ch+1:0];
    const float* xbase = &sm[((ch&1) ? OFF_X1 : OFF_X0)];
    #pragma unroll
    for (int j=0;j<2;++j){
      const int k = (j<<7) + (s<<2);
      float4 xv[8];
      #pragma unroll
      for (int b=0;b<8;++b) xv[b] = *(const float4*)&xbase[(b<<8) + k];
      #pragma unroll
      for (int i=0;i<2;++i){
        float4 wv = wr[j][i];
        #pragma unroll
        for (int b=0;b<8;++b){
          acc[i][b] = fmaf(wv.x, xv[b].x, acc[i][b]);
          acc[i][b] = fmaf(wv.y, xv[b].y, acc[i][b]);
          acc[i][b] = fmaf(wv.z, xv[b].z, acc[i][b]);
          acc[i][b] = fmaf(wv.w, xv[b].w, acc[i][b]);
        }
      }
    }
    __syncthreads();
  }
  return reduce_dot(sm, acc);
}

// issue the epilogue's LLC loads BEFORE the gemm so their latency hides
__device__ __forceinline__ float prefetch_gh(const float* gh, int u0){
  const int tid = threadIdx.x;
  if (tid >= 256) return 0.f;
  int row32 = tid >> 3, b = tid & 7;
  int gate = row32 >> 3, ul = row32 & 7;
  return ldg_sc1(&gh[(((gate<<10) + u0 + ul)<<3) + b]);
}
__device__ __forceinline__ float prefetch_h(const float* h, int u0){
  const int tid = threadIdx.x;
  if (tid >= 64) return 0.f;
  return ldg_sc1(&h[((tid&7)<<10) + u0 + (tid>>3)]);
}

__device__ void lstm_epilogue(float* sm, float dot, float ghb,
                              const float* __restrict__ bias, float hold,
                              float* __restrict__ h, float* __restrict__ c, int u0)
{
  const int tid = threadIdx.x;
  if (tid < 256){
    int row32 = tid >> 3;
    int gate = row32 >> 3, ul = row32 & 7;
    sm[OFF_EXG + tid] = dot + bias[(gate<<10) + u0 + ul] + ghb;
  }
  __syncthreads();
  if (tid < 64){
    float gi = sm[OFF_EXG + tid];
    float gf = sm[OFF_EXG + 64 + tid];
    float gg = sm[OFF_EXG + 128 + tid];
    float go = sm[OFF_EXG + 192 + tid];
    int ul2 = tid >> 3, b2 = tid & 7;
    int hi = (b2<<10) + u0 + ul2;
    float co = c[hi];               // block-private: cached
    float cn = fsig_(gf)*co + fsig_(gi)*ftanh_(gg);
    float hn = fsig_(go)*ftanh_(cn);
    c[hi] = 0.9f*cn + 0.1f*co;
    stg_sc1(&h[hi], 0.9f*hn + 0.1f*hold);
  }
}

// one output row per wave: rr = b*81 + r (r==80 -> stop)
__device__ void outstop_wave(int rr, int tp, int par,
    const float* __restrict__ feat_W, const float* __restrict__ stop_W,
    const float* __restrict__ stop_b, const float* __restrict__ h1,
    const float* __restrict__ attc, const float* __restrict__ iSw,
    float* __restrict__ d_out)
{
  if (rr >= 648) return;
  int b = rr / 81, r = rr - 81*b;
  int lane = threadIdx.x & 63;
  const float4* Wr = (const float4*)((r < 80) ? (feat_W + (size_t)r*1536) : stop_W);
  float inv = ldg_sc1(iSw + (par<<3) + b);
  float acc = 0.f, acc2 = 0.f;
  #pragma unroll
  for (int j=0;j<4;++j){
    int p = lane + (j<<6);
    float4 w = Wr[p], x = ldg4_sc1(h1 + (b<<10) + (p<<2));
    acc = fmaf(w.x,x.x, fmaf(w.y,x.y, fmaf(w.z,x.z, fmaf(w.w,x.w, acc))));
  }
  #pragma unroll
  for (int j=4;j<6;++j){
    int p = lane + (j<<6);
    float4 w = Wr[p], x = ldg4_sc1(attc + (par<<12) + (b<<9) + ((p-256)<<2));
    acc2 = fmaf(w.x,x.x, fmaf(w.y,x.y, fmaf(w.z,x.z, fmaf(w.w,x.w, acc2))));
  }
  acc += acc2 * inv;
  acc += __shfl_down(acc, 32, 64);
  acc += __shfl_down(acc, 16, 64);
  acc += __shfl_down(acc,  8, 64);
  acc += __shfl_down(acc,  4, 64);
  acc += __shfl_down(acc,  2, 64);
  acc += __shfl_down(acc,  1, 64);
  if (lane == 0){
    if (r < 80) d_out[((size_t)b*TDz + tp)*ODz + r] = acc;
    else        d_out[96000 + (size_t)b*TDz + tp] = acc + stop_b[0];
  }
}

extern "C" __global__ void __launch_bounds__(NT, 1) dec_kernel(
  const float* __restrict__ memory, const int* __restrict__ mlen, const float* __restrict__ targets,
  const float* __restrict__ W_mem, const float* __restrict__ W_q, const float* __restrict__ W_loc,
  const float* __restrict__ loc_f, const float* __restrict__ attn_v, const float* __restrict__ attn_b,
  const float* __restrict__ pre_W1, const float* __restrict__ pre_b1,
  const float* __restrict__ pre_W2, const float* __restrict__ pre_b2,
  const float* __restrict__ Wi0, const float* __restrict__ Wh0, const float* __restrict__ bl0,
  const float* __restrict__ Wi1, const float* __restrict__ Wh1, const float* __restrict__ bl1,
  const float* __restrict__ feat_W, const float* __restrict__ stop_W, const float* __restrict__ stop_b,
  float* __restrict__ d_out, float* __restrict__ ws)
{
  __shared__ float sm[SM_TOTF];
  const int blk = blockIdx.x, tid = threadIdx.x;

  float* Pw   = ws + OF_P;
  float* pmT  = ws + OF_PM;
  float* qw   = ws + OF_Q;
  float* uw   = ws + OF_U;
  float* cum  = ws + OF_CUM;
  float* attc = ws + OF_ATTC;
  float* Sw   = ws + OF_S;
  float* iSw  = ws + OF_INVS;
  float* h0 = ws + OF_H0; float* c0 = ws + OF_C0;
  float* h1 = ws + OF_H1; float* c1 = ws + OF_C1;
  float* gh0 = ws + OF_GH0; float* gh1 = ws + OF_GH1;
  int* bar = (int*)(ws + OF_BAR);
  int bt = 0;

  const bool is_attn = (blk < 64);
  const int ab  = blk >> 3;          // attention batch
  const int ai0 = (blk & 7) << 6;    // attention base position
  const int il  = tid & 63;          // position within slice
  const int ag  = tid >> 6;          // feature group (0..7)

  // ------------------------- INIT (every launch) ---------------------------
  {
    const int gs = NB*NT;
    const int gid = blk*NT + tid;
    for (int i = gid; i < 98304; i += gs) h0[i] = 0.f;    // h0,c0,h1,c1,gh0,gh1
    for (int i = gid; i < 1024;  i += gs) qw[i]  = 0.f;
    for (int i = gid; i < 4096;  i += gs) cum[i] = 0.f;
    for (int i = gid; i < 8192;  i += gs) attc[i] = 0.f;
    if (gid < 32) Sw[gid] = 0.f;                          // S + invS

    // persistent weights -> LDS fp16
    if (blk < 124){
      load_wtile<768, true >(&sm[OFF_WA], Wi0, blk<<3);
      load_wtile<1024,false>(&sm[OFF_WB], Wh0, blk<<5);
    } else if (blk < 128){
      load_wtile<768, true >(&sm[OFF_WA], Wi0, blk<<3);
      load_wtile<1024,false>(&sm[OFF_WB], W_q, (blk-124)<<5);
    } else {
      load_wtile<1024,false>(&sm[OFF_WG1], Wh1, (blk-128)<<5);
      load_wtile<1024,true >(&sm[OFF_WG2], Wi1, (blk-128)<<3);
    }

    if (is_attn){
      // pmT[a][il] = mem[ab, ai0+il, :] . W_mem[a,:] + attn_b[a]
      float pacc[16];
      #pragma unroll
      for (int j=0;j<16;++j) pacc[j] = 0.f;
      for (int dc=0; dc<4; ++dc){
        for (int idx = tid; idx < 8192; idx += NT){
          int r = idx >> 7, d = idx & 127;
          sm[r*129 + d] = memory[(size_t)((ab<<9)+ai0+r)*DINz + (dc<<7) + d];
        }
        __syncthreads();
        #pragma unroll
        for (int j=0;j<16;++j){
          int a = (ag<<4) + j;
          const float* wr = W_mem + (size_t)a*DINz + (dc<<7);
          const float* mr = &sm[il*129];
          float acc = 0.f;
          for (int d=0; d<128; d+=4){
            acc = fmaf(mr[d  ], wr[d  ], acc);
            acc = fmaf(mr[d+1], wr[d+1], acc);
            acc = fmaf(mr[d+2], wr[d+2], acc);
            acc = fmaf(mr[d+3], wr[d+3], acc);
          }
          pacc[j] += acc;
        }
        __syncthreads();
      }
      #pragma unroll
      for (int j=0;j<16;++j){
        int a = (ag<<4) + j;
        pmT[((size_t)blk<<13) + (a<<6) + il] = pacc[j] + attn_b[a];
      }
      // persistent slabs: F = W_loc @ filters, v
      for (int idx = tid; idx < ATz*KFz; idx += NT){
        int a = idx / KFz, k = idx - a*KFz;
        float s2 = 0.f;
        #pragma unroll
        for (int c2=0;c2<LOCz;++c2) s2 = fmaf(W_loc[(a<<5)+c2], loc_f[c2*KFz+k], s2);
        sm[OFF_F + idx] = s2;
      }
      if (tid < 128) sm[OFF_V + tid] = attn_v[tid];
      __syncthreads();
    }

    // prenet for all (t,b) pairs; scratch in sm[0..1023]
    const int th = tid >> 8, t2 = tid & 255, base = th << 9;
    for (int it=0; it<3; ++it){
      int pp = (blk<<1) + th + (it<<9);
      bool act = pp < 1200;
      if (act && t2 < ODz){
        int tt = pp >> 3, bb = pp & 7;
        sm[base + t2] = (tt==0) ? 0.f : targets[((size_t)bb*TDz + (tt-1))*ODz + t2];
      }
      __syncthreads();
      if (act){
        float a1 = pre_b1[t2];
        for (int k=0;k<ODz;++k) a1 = fmaf(pre_W1[t2*ODz+k], sm[base+k], a1);
        sm[base + 128 + t2] = fmaxf(a1, 0.f);
      }
      __syncthreads();
      if (act){
        float a2 = pre_b2[t2];
        for (int k=0;k<PREz;++k) a2 = fmaf(pre_W2[(t2<<8)+k], sm[base+128+k], a2);
        Pw[((size_t)pp<<8) + t2] = fmaxf(a2, 0.f);
      }
      __syncthreads();
    }
  }
  grid_barrier_heavy(bar, ++bt);

  // ------------------------------ MAIN LOOP (3 phases) ---------------------
  for (int t = 0; t < TDz; ++t){
    const int cur = t & 1, prv = cur ^ 1;

    // ---- P1: attention (0-63) | gh0 tail (64-67, streamed) | gh1 (128-255)
    if (is_attn){
      if (tid < 94){
        int gi = ai0 - 15 + tid;
        sm[OFF_CW + tid] = (gi >= 0 && gi < TE) ? ldg_sc1(&cum[(ab<<9)+gi]) : 0.f;
      }
      if (tid < 128) sm[OFF_QS + tid] = ldg_sc1(&qw[(tid<<3) + ab]);
      __syncthreads();
      float part = 0.f;
      #pragma unroll
      for (int j=0;j<16;++j){
        int a = (ag<<4) + j;
        const float* fb = &sm[OFF_F + a*KFz];
        float conv = 0.f;
        #pragma unroll
        for (int k=0;k<KFz;++k) conv = fmaf(fb[k], sm[OFF_CW + il + k], conv);
        float pv = pmT[((size_t)blk<<13) + (a<<6) + il];
        part = fmaf(sm[OFF_V + a], ftanh_(pv + sm[OFF_QS + a] + conv), part);
      }
      sm[OFF_PART + (il<<3) + ag] = part;
      __syncthreads();
      if (tid < 64){
        float e = 0.f;
        #pragma unroll
        for (int k=0;k<8;++k) e += sm[OFF_PART + (tid<<3) + k];
        int gi = ai0 + tid;
        float uu = (gi < mlen[ab]) ? __expf(e) : 0.f;
        stg_sc1(&uw[(ab<<9)+gi], uu);
        sm[OFF_UU + tid] = uu;
      }
      __syncthreads();
      if (tid == 0){
        float ssum = 0.f;
        #pragma unroll
        for (int k=0;k<64;++k) ssum += sm[OFF_UU + k];
        atomicAdd(&Sw[(cur<<3)+ab], ssum);
      }
      {
        float acc = 0.f;
        const float* mrow = memory + (size_t)((ab<<9)+ai0)*DINz + tid;
        #pragma unroll 4
        for (int i=0;i<64;++i)
          acc = fmaf(sm[OFF_UU + i], mrow[(size_t)i*DINz], acc);
        atomicAdd(&attc[(cur<<12) + (ab<<9) + tid], acc);
      }
    } else if (blk < 68){
      const int tile = 124 + (blk - 64);
      float dot = gemm32x8_gw(sm, Wh0, tile<<5, h0);
      if (tid < 256) stg_sc1(&gh0[(tile<<8) + tid], dot);
    } else if (blk >= 128){
      const int tile = blk - 128;
      float dot = gemm32x8_lds<1024,0>(sm, (const __half*)&sm[OFF_WG1], h1,
                                       nullptr, nullptr, nullptr);
      if (tid < 256) stg_sc1(&gh1[(tile<<8) + tid], dot);
    }
    grid_barrier(bar, ++bt);

    // ---- P2: LSTM0 (0-127) | attw/cum (128-135) | outstop t-1 (136-216) ---
    if (blk < 128){
      const int u0 = blk << 3;
      float ghb  = prefetch_gh(gh0, u0);
      float hold = prefetch_h(h0, u0);
      float dot = gemm32x8_lds<768,1>(sm, (const __half*)&sm[OFF_WA], nullptr,
                                      attc + (cur<<12), Sw + (cur<<3),
                                      Pw + ((size_t)t<<11));
      lstm_epilogue(sm, dot, ghb, bl0, hold, h0, c0, u0);
    } else if (blk < 136){
      const int b = blk - 128;
      float Sv = __hip_atomic_load(&Sw[(cur<<3)+b], __ATOMIC_RELAXED, AG);
      float inv = 1.f / Sv;
      if (tid == 0) stg_sc1(&iSw[(cur<<3)+b], inv);
      for (int i = tid; i < TE; i += NT){
        float u = ldg_sc1(&uw[(b<<9)+i]);
        float w = u * inv;
        d_out[97200 + ((size_t)b*TDz + t)*TE + i] = w;
        stg_sc1(&cum[(b<<9)+i], ldg_sc1(&cum[(b<<9)+i]) + w);
      }
    } else if (blk < 217){
      if (t > 0)
        outstop_wave((blk-136)*8 + (tid>>6), t-1, prv,
                     feat_W, stop_W, stop_b, h1, attc, iSw, d_out);
    }
    grid_barrier(bar, ++bt);

    // ---- P3: gh0 0-123 | Wq + zero duties (124-127) | LSTM1 (128-255) ----
    if (blk < 124){
      float dot = gemm32x8_lds<1024,0>(sm, (const __half*)&sm[OFF_WB], h0,
                                       nullptr, nullptr, nullptr);
      if (tid < 256) stg_sc1(&gh0[(blk<<8) + tid], dot);
    } else if (blk < 128){
      const int rt = blk - 124;
      float dot = gemm32x8_lds<1024,0>(sm, (const __half*)&sm[OFF_WB], h0,
                                       nullptr, nullptr, nullptr);
      if (tid < 256) stg_sc1(&qw[(rt<<8) + tid], dot);
      const int zbase = (prv<<12) + (rt<<10);
      for (int i = tid; i < 1024; i += NT) stg_sc1(&attc[zbase + i], 0.f);
      if (rt == 0 && tid < 8) stg_sc1(&Sw[(prv<<3)+tid], 0.f);
    } else {
      const int u0 = (blk - 128) << 3;
      float ghb  = prefetch_gh(gh1, u0);
      float hold = prefetch_h(h1, u0);
      float dot = gemm32x8_lds<1024,0>(sm, (const __half*)&sm[OFF_WG2], h0,
                                       nullptr, nullptr, nullptr);
      lstm_epilogue(sm, dot, ghb, bl1, hold, h1, c1, u0);
    }
    grid_barrier(bar, ++bt);
  }

  // final out/stop for t = 149 (parity 1)
  if (blk >= 136 && blk < 217)
    outstop_wave((blk-136)*8 + (tid>>6), TDz-1, 1,
                 feat_W, stop_W, stop_b, h1, attc, iSw, d_out);
}

extern "C" void kernel_launch(void* const* d_in, const int* in_sizes, int n_in,
                              void* d_out, int out_size, void* d_ws, size_t ws_size,
                              hipStream_t stream)
{
  (void)in_sizes; (void)n_in; (void)out_size; (void)ws_size;
  (void)hipMemsetAsync((char*)d_ws + (size_t)OF_BAR*4, 0, 18432, stream);
  dec_kernel<<<dim3(NB), dim3(NT), 0, stream>>>(
    (const float*)d_in[0],  (const int*)d_in[1],   (const float*)d_in[2],
    (const float*)d_in[3],  (const float*)d_in[4],  (const float*)d_in[5],
    (const float*)d_in[6],  (const float*)d_in[7],  (const float*)d_in[8],
    (const float*)d_in[9],  (const float*)d_in[10], (const float*)d_in[11], (const float*)d_in[12],
    (const float*)d_in[13], (const float*)d_in[14], (const float*)d_in[15],
    (const float*)d_in[16], (const float*)d_in[17], (const float*)d_in[18],
    (const float*)d_in[19], (const float*)d_in[20], (const float*)d_in[21],
    (float*)d_out, (float*)d_ws);
}